// Round 3
// baseline (189.426 us; speedup 1.0000x reference)
//
#include <hip/hip_runtime.h>
#include <hip/hip_bf16.h>

#define N_SRCN 200000
#define N_DSTN 50000
#define NEDGE 800000
#define KIN 256
#define NF 192        // H*OUT = 3*64
#define SLOPE 0.2f

typedef __attribute__((ext_vector_type(8))) short bf16x8;
typedef __attribute__((ext_vector_type(4))) float f32x4;

__device__ __forceinline__ unsigned short f2bf(float f) {
    union { float f; unsigned int u; } v; v.f = f;
    unsigned int u = v.u;
    return (unsigned short)((u + 0x7FFFu + ((u >> 16) & 1u)) >> 16);  // RNE
}
__device__ __forceinline__ float bf2f(unsigned short h) {
    union { unsigned int u; float f; } v; v.u = ((unsigned int)h) << 16;
    return v.f;
}
__device__ __forceinline__ unsigned int cvt2(float lo, float hi) {
    __hip_bfloat162 h = __float22bfloat162_rn(float2{lo, hi});
    union { __hip_bfloat162 h; unsigned int u; } c; c.h = h;
    return c.u;
}

// ---------------- prep: pack W (f32 [192][256]) into bf16 fragment-major -----
// Wp[((ks*12 + nt)*64 + lane)*8 + j] = bf16(W[nt*16 + (lane&15)][ks*32 + (lane>>4)*8 + j])
__global__ void prep_w(const float* __restrict__ W, unsigned short* __restrict__ Wp) {
    int tid = blockIdx.x * blockDim.x + threadIdx.x;
    if (tid >= 12 * 8 * 64) return;
    int lane = tid & 63;
    int g = tid >> 6;
    int nt = g % 12, ks = g / 12;
    int col = nt * 16 + (lane & 15);
    int k = ks * 32 + (lane >> 4) * 8;
    const float* wsrc = &W[col * KIN + k];
    unsigned short* o = &Wp[tid * 8];
    #pragma unroll
    for (int j = 0; j < 8; ++j) o[j] = f2bf(wsrc[j]);
}

// ---------------- row_ptr: lower_bound of each d in sorted dst ----------------
__global__ void rowptr_kernel(const int* __restrict__ dst, int* __restrict__ rp) {
    int d = blockIdx.x * blockDim.x + threadIdx.x;
    if (d > N_DSTN) return;
    int lo = 0, hi = NEDGE;
    while (lo < hi) {
        int mid = (lo + hi) >> 1;
        if (dst[mid] < d) lo = mid + 1; else hi = mid;
    }
    rp[d] = lo;
}

// ---------------- GEMM: feat = x @ W^T (bf16 MFMA) + fused el/er -------------
// Wave w owns rows [blk*64 + w*16, +16), ALL 192 cols. No LDS, no barrier.
// ALL 16 A-fragment float4 loads issued up front (one HBM latency per wave,
// 16-deep MLP); B-frags stream from packed bf16 W via L1/L2.
__launch_bounds__(256, 2)
__global__ void gemm_feat(const float* __restrict__ x, const unsigned short* __restrict__ Wp,
                          const float* __restrict__ attn_l, const float* __restrict__ attn_r,
                          unsigned short* __restrict__ feat,
                          float* __restrict__ el, float* __restrict__ er) {
    const int t = threadIdx.x;
    const int wid = t >> 6, lane = t & 63;
    const int al = lane & 15, ah = lane >> 4;
    const int r0 = blockIdx.x * 64 + wid * 16;

    const float* xrow = &x[(size_t)(r0 + al) * KIN + ah * 8];

    // ---- issue ALL A loads first (16 x dwordx4 in flight) ----
    float4 a[16];
    #pragma unroll
    for (int ks = 0; ks < 8; ++ks) {
        a[2 * ks]     = *(const float4*)&xrow[ks * 32];
        a[2 * ks + 1] = *(const float4*)&xrow[ks * 32 + 4];
    }

    f32x4 acc[12] = {};
    #pragma unroll
    for (int ks = 0; ks < 8; ++ks) {
        union { bf16x8 v; unsigned int u[4]; } av;
        av.u[0] = cvt2(a[2 * ks].x,     a[2 * ks].y);
        av.u[1] = cvt2(a[2 * ks].z,     a[2 * ks].w);
        av.u[2] = cvt2(a[2 * ks + 1].x, a[2 * ks + 1].y);
        av.u[3] = cvt2(a[2 * ks + 1].z, a[2 * ks + 1].w);
        const unsigned short* wbase = &Wp[(size_t)(ks * 12) * 512 + lane * 8];
        #pragma unroll
        for (int nt = 0; nt < 12; ++nt) {
            bf16x8 bv = *(const bf16x8*)&wbase[nt * 512];
            acc[nt] = __builtin_amdgcn_mfma_f32_16x16x32_bf16(av.v, bv, acc[nt], 0, 0, 0);
        }
    }

    // epilogue 1: feat store (C/D layout: col=al+nt*16, row=ah*4+e  [m89])
    #pragma unroll
    for (int nt = 0; nt < 12; ++nt) {
        const int col = nt * 16 + al;
        #pragma unroll
        for (int e = 0; e < 4; ++e) {
            const int row = r0 + ah * 4 + e;
            feat[(size_t)row * NF + col] = f2bf(acc[nt][e]);
        }
    }

    // epilogue 2: fused el/er (wave holds full rows). head h = cols [h*64, h*64+64)
    float Al[12], Ar[12];
    #pragma unroll
    for (int nt = 0; nt < 12; ++nt) {
        Al[nt] = attn_l[nt * 16 + al];
        Ar[nt] = attn_r[nt * 16 + al];
    }
    #pragma unroll
    for (int h = 0; h < 3; ++h) {
        #pragma unroll
        for (int e = 0; e < 4; ++e) {
            float sl = 0.f, sr = 0.f;
            #pragma unroll
            for (int q = 0; q < 4; ++q) {
                const int nt = h * 4 + q;
                sl += acc[nt][e] * Al[nt];
                sr += acc[nt][e] * Ar[nt];
            }
            #pragma unroll
            for (int m = 1; m <= 8; m <<= 1) {
                sl += __shfl_xor(sl, m);
                sr += __shfl_xor(sr, m);
            }
            if (al == 0) {
                const int row = r0 + ah * 4 + e;
                el[row * 3 + h] = sl;
                if (row < N_DSTN) er[row * 3 + h] = sr;
            }
        }
    }
}

// ---------------- gather: edge softmax (no max shift) + weighted accumulate --
// one wave per dst node; lane owns feature `lane` of each head.
// Edge loop unrolled x8, loads issued before use (8-edge x 3-head = 24-deep MLP).
__launch_bounds__(256)
__global__ void gather_kernel(const unsigned short* __restrict__ feat,
                              const float* __restrict__ el, const float* __restrict__ er,
                              const int* __restrict__ src, const int* __restrict__ rp,
                              float* __restrict__ out) {
    const int lane = threadIdx.x & 63;
    const int d = (blockIdx.x * blockDim.x + threadIdx.x) >> 6;
    if (d >= N_DSTN) return;
    const int lo = rp[d], hi = rp[d + 1];
    const float er0 = er[d * 3 + 0], er1 = er[d * 3 + 1], er2 = er[d * 3 + 2];

    float a0 = 0.f, a1 = 0.f, a2 = 0.f, s0 = 0.f, s1 = 0.f, s2 = 0.f;
    for (int base = lo; base < hi; base += 64) {
        const int cnt = min(64, hi - base);
        int sv = 0; float w0 = 0.f, w1 = 0.f, w2 = 0.f;
        if (lane < cnt) {
            sv = src[base + lane];
            float e0 = el[sv * 3 + 0] + er0; e0 = e0 >= 0.f ? e0 : SLOPE * e0; w0 = __expf(e0);
            float e1 = el[sv * 3 + 1] + er1; e1 = e1 >= 0.f ? e1 : SLOPE * e1; w1 = __expf(e1);
            float e2 = el[sv * 3 + 2] + er2; e2 = e2 >= 0.f ? e2 : SLOPE * e2; w2 = __expf(e2);
        }
        int j = 0;
        for (; j + 8 <= cnt; j += 8) {
            unsigned short f0[8], f1[8], f2[8];
            float u0[8], u1[8], u2[8];
            #pragma unroll
            for (int q = 0; q < 8; ++q) {
                const int sj = __shfl(sv, j + q);
                const unsigned short* fp = &feat[(size_t)sj * NF + lane];
                f0[q] = fp[0]; f1[q] = fp[64]; f2[q] = fp[128];
                u0[q] = __shfl(w0, j + q);
                u1[q] = __shfl(w1, j + q);
                u2[q] = __shfl(w2, j + q);
            }
            #pragma unroll
            for (int q = 0; q < 8; ++q) {
                s0 += u0[q]; a0 += u0[q] * bf2f(f0[q]);
                s1 += u1[q]; a1 += u1[q] * bf2f(f1[q]);
                s2 += u2[q]; a2 += u2[q] * bf2f(f2[q]);
            }
        }
        for (; j < cnt; ++j) {
            const int sj = __shfl(sv, j);
            const float u0 = __shfl(w0, j);
            const float u1 = __shfl(w1, j);
            const float u2 = __shfl(w2, j);
            const unsigned short* fp = &feat[(size_t)sj * NF + lane];
            s0 += u0; a0 += u0 * bf2f(fp[0]);
            s1 += u1; a1 += u1 * bf2f(fp[64]);
            s2 += u2; a2 += u2 * bf2f(fp[128]);
        }
    }
    if (hi == lo) { s0 = 1.f; s1 = 1.f; s2 = 1.f; }
    float* op = &out[(size_t)d * NF];
    op[lane]       = a0 / s0;
    op[64 + lane]  = a1 / s1;
    op[128 + lane] = a2 / s2;
}

extern "C" void kernel_launch(void* const* d_in, const int* in_sizes, int n_in,
                              void* d_out, int out_size, void* d_ws, size_t ws_size,
                              hipStream_t stream) {
    const float* x      = (const float*)d_in[0];
    const float* W      = (const float*)d_in[1];
    const float* attn_l = (const float*)d_in[2];
    const float* attn_r = (const float*)d_in[3];
    const int*   src    = (const int*)d_in[4];
    const int*   dst    = (const int*)d_in[5];
    float* out = (float*)d_out;

    char* ws = (char*)d_ws;
    unsigned short* feat = (unsigned short*)ws;             // 76,800,000 B
    float* el = (float*)(ws + 76800000);                    //  2,400,000 B
    float* er = (float*)(ws + 79200000);                    //    600,000 B
    unsigned short* Wp = (unsigned short*)(ws + 79800000);  //     98,304 B
    int*   rp = (int*)(ws + 79898304);                      //    200,004 B

    prep_w<<<24, 256, 0, stream>>>(W, Wp);
    rowptr_kernel<<<(N_DSTN + 1 + 255) / 256, 256, 0, stream>>>(dst, rp);
    gemm_feat<<<3125, 256, 0, stream>>>(x, Wp, attn_l, attn_r, feat, el, er);
    gather_kernel<<<12500, 256, 0, stream>>>(feat, el, er, src, rp, out);
}